// Round 6
// baseline (1235.676 us; speedup 1.0000x reference)
//
#include <hip/hip_runtime.h>
#include <hip/hip_fp16.h>
#include <math.h>

#define N_NODES 50000
#define N_EDGES 800000
#define MPAD 50048            // 391 * 128, so GEMM needs no M bounds checks
#define KPHYS 1024            // A2 physical row width: [hi(512) | lo(512)]
#define KVIRT 1536            // virtual K: hi*hi + lo*hi + hi*lo

// ---------------- bf16 helpers ----------------

__device__ __forceinline__ unsigned short bf16_rn(float f) {
    unsigned u = __float_as_uint(f);
    u += 0x7FFFu + ((u >> 16) & 1u);  // round-to-nearest-even
    return (unsigned short)(u >> 16);
}
__device__ __forceinline__ float bf16_f32(unsigned short h) {
    return __uint_as_float(((unsigned)h) << 16);
}

// ---------------- degree / CSR build ----------------

__global__ void zero_int_kernel(int* __restrict__ p, int n) {
    int i = blockIdx.x * blockDim.x + threadIdx.x;
    if (i < n) p[i] = 0;
}

__global__ void count_deg_kernel(const int* __restrict__ dst, int* __restrict__ deg) {
    int e = blockIdx.x * blockDim.x + threadIdx.x;
    if (e < N_EDGES) atomicAdd(&deg[dst[e]], 1);
}

__global__ void dinv_kernel(const int* __restrict__ deg, float* __restrict__ dinv) {
    int i = blockIdx.x * blockDim.x + threadIdx.x;
    if (i < N_NODES) dinv[i] = rsqrtf((float)deg[i] + 1.0f);  // +1 self-loop
}

__global__ __launch_bounds__(1024) void scan_kernel(const int* __restrict__ deg,
                                                    int* __restrict__ offsets,
                                                    int* __restrict__ cursor) {
    __shared__ int sm[1024];
    int t = threadIdx.x;
    int base = 0;
    if (t == 0) offsets[0] = 0;
    for (int start = 0; start < N_NODES; start += 1024) {
        int i = start + t;
        int v = (i < N_NODES) ? deg[i] : 0;
        sm[t] = v;
        __syncthreads();
        for (int off = 1; off < 1024; off <<= 1) {
            int x = (t >= off) ? sm[t - off] : 0;
            __syncthreads();
            sm[t] += x;
            __syncthreads();
        }
        if (i < N_NODES) {
            offsets[i + 1] = base + sm[t];
            cursor[i] = base + sm[t] - v;
        }
        base += sm[1023];
        __syncthreads();
    }
}

__global__ void fill_csr_kernel(const int* __restrict__ src, const int* __restrict__ dst,
                                int* __restrict__ cursor, int* __restrict__ csr_src,
                                float* __restrict__ csr_w, const float* __restrict__ dinv) {
    int e = blockIdx.x * blockDim.x + threadIdx.x;
    if (e < N_EDGES) {
        int s = src[e], d = dst[e];
        int p = atomicAdd(&cursor[d], 1);
        csr_src[p] = s;
        csr_w[p] = dinv[s] * dinv[d];
    }
}

// ---------------- split-bf16 MFMA GEMM (+ fp16 mirror output) ----------------
// LDS staged in MFMA-fragment order: chunk c (16B) = [frag = c>>6][lane = c&63],
// lane = quad*16 + l15 -> global row (c>>6)*16 + (c&15), k-chunk (c>>4)&3.
// Fragment reads are then lane-contiguous b128 (conflict-free, 2-way alias only).

typedef __attribute__((ext_vector_type(8))) short bf16x8;
typedef __attribute__((ext_vector_type(4))) float floatx4;

#define GLL16(g, l)                                                                   \
    __builtin_amdgcn_global_load_lds((__attribute__((address_space(1))) const void*)(g), \
                                     (__attribute__((address_space(3))) void*)(l), 16, 0, 0)

__global__ __launch_bounds__(256) void gemm_split_bt(const unsigned short* __restrict__ A2,
                                                     const unsigned short* __restrict__ B2T,
                                                     float* __restrict__ C,
                                                     __half* __restrict__ C16, int N) {
    __shared__ unsigned short As[128 * 32];  // fragment-order chunks
    __shared__ unsigned short Bs[128 * 32];

    const int t = threadIdx.x;
    const int lane = t & 63;
    const int quad = lane >> 4;
    const int l15 = lane & 15;
    const int w = t >> 6;
    const int wm = w & 1, wn = w >> 1;
    const int row0 = blockIdx.x * 128;
    const int col0 = blockIdx.y * 128;

    floatx4 acc[4][4];
#pragma unroll
    for (int i = 0; i < 4; i++)
#pragma unroll
        for (int j = 0; j < 4; j++) acc[i][j] = (floatx4){0.f, 0.f, 0.f, 0.f};

    // swizzled staging: thread t stages global (row sr, k-chunk sk) into LDS chunk t
    const int sr = ((t >> 6) << 4) + (t & 15);  // wave*16 + (t&15), in [0,64)
    const int sk = ((t >> 4) & 3) * 8;
    const unsigned short* Arow0 = A2 + (size_t)(row0 + sr) * KPHYS + sk;
    const unsigned short* Arow1 = Arow0 + (size_t)64 * KPHYS;
    const unsigned short* Brow0 = B2T + (size_t)(col0 + sr) * KVIRT + sk;
    const unsigned short* Brow1 = Brow0 + (size_t)64 * KVIRT;
    unsigned short* lA0 = As + t * 8;
    unsigned short* lA1 = As + 2048 + t * 8;
    unsigned short* lB0 = Bs + t * 8;
    unsigned short* lB1 = Bs + 2048 + t * 8;

    for (int kb = 0; kb < KVIRT; kb += 32) {
        const int kA = (kb < KPHYS) ? kb : kb - KPHYS;  // virtual hi-replay wraps onto physical hi
        __syncthreads();
        GLL16(Arow0 + kA, lA0);
        GLL16(Arow1 + kA, lA1);
        GLL16(Brow0 + kb, lB0);
        GLL16(Brow1 + kb, lB1);
        __syncthreads();

        bf16x8 af[4], bf[4];
#pragma unroll
        for (int mt = 0; mt < 4; mt++)
            af[mt] = *(const bf16x8*)(As + ((wm * 4 + mt) * 64 + lane) * 8);
#pragma unroll
        for (int nt = 0; nt < 4; nt++)
            bf[nt] = *(const bf16x8*)(Bs + ((wn * 4 + nt) * 64 + lane) * 8);
#pragma unroll
        for (int mt = 0; mt < 4; mt++)
#pragma unroll
            for (int nt = 0; nt < 4; nt++)
                acc[mt][nt] = __builtin_amdgcn_mfma_f32_16x16x32_bf16(af[mt], bf[nt], acc[mt][nt], 0, 0, 0);
    }

#pragma unroll
    for (int mt = 0; mt < 4; mt++) {
#pragma unroll
        for (int r = 0; r < 4; r++) {
            int row = row0 + wm * 64 + mt * 16 + quad * 4 + r;
            float* Cp = C + (size_t)row * N + col0 + wn * 64 + l15;
            __half* Cp16 = C16 + (size_t)row * N + col0 + wn * 64 + l15;
#pragma unroll
            for (int nt = 0; nt < 4; nt++) {
                Cp[nt * 16] = acc[mt][nt][r];
                Cp16[nt * 16] = __float2half(acc[mt][nt][r]);
            }
        }
    }
}

// ---------------- weight split (W [K x N] fp32 -> B2T [N x KVIRT] bf16) ----------------

__global__ void wsplit_kernel(const float* __restrict__ W, unsigned short* __restrict__ B2T, int N) {
    int idx = blockIdx.x * blockDim.x + threadIdx.x;
    if (idx >= 512 * N) return;
    int k = idx / N, n = idx % N;
    float v = W[(size_t)k * N + n];
    unsigned short hi = bf16_rn(v);
    unsigned short lo = bf16_rn(v - bf16_f32(hi));
    unsigned short* row = B2T + (size_t)n * KVIRT;
    row[k] = hi;
    row[512 + k] = hi;
    row[1024 + k] = lo;
}

// ---------------- x split (fp32 [N_NODES x 512] -> A2 [MPAD x KPHYS]) ----------------

__global__ __launch_bounds__(256) void split_x_kernel(const float* __restrict__ x,
                                                      unsigned short* __restrict__ A2) {
    int m = blockIdx.x;
    int ch = threadIdx.x * 2;
    unsigned short* arow = A2 + (size_t)m * KPHYS;
    float vx = 0.f, vy = 0.f;
    if (m < N_NODES) {
        float2 v = *(const float2*)(x + (size_t)m * 512 + ch);
        vx = v.x;
        vy = v.y;
    }
    unsigned short hx = bf16_rn(vx), hy = bf16_rn(vy);
    arow[ch] = hx;
    arow[ch + 1] = hy;
    arow[512 + ch] = bf16_rn(vx - bf16_f32(hx));
    arow[512 + ch + 1] = bf16_rn(vy - bf16_f32(hy));
}

// ---------------- aggregation ----------------

__device__ __forceinline__ float gelu_tanh(float x) {
    float x3 = x * x * x;
    float inner = 0.7978845608028654f * (x + 0.044715f * x3);
    return 0.5f * x * (1.0f + tanhf(inner));
}

// One wave per node: 64 lanes x 8 fp16 ch = 512 ch. 4 nodes per 256-thread block.
__global__ __launch_bounds__(256) void aggregate_split_kernel(
    const float* __restrict__ h32, const __half* __restrict__ h16,
    const int* __restrict__ offsets, const int* __restrict__ csr_src,
    const float* __restrict__ csr_w, const float* __restrict__ dinv,
    const float* __restrict__ bias, unsigned short* __restrict__ A2) {
    int t = threadIdx.x;
    int node = __builtin_amdgcn_readfirstlane(blockIdx.x * 4 + (t >> 6));
    int ch = (t & 63) * 8;
    unsigned short* arow = A2 + (size_t)node * KPHYS;
    if (node >= N_NODES) {  // zero pad rows (16B per store)
        *(uint4*)(arow + ch) = make_uint4(0, 0, 0, 0);
        *(uint4*)(arow + 512 + ch) = make_uint4(0, 0, 0, 0);
        return;
    }
    int p0 = offsets[node], p1 = offsets[node + 1];
    float a[8] = {0.f, 0.f, 0.f, 0.f, 0.f, 0.f, 0.f, 0.f};

    union H8 { float4 f4; __half2 h2[4]; };
    int p = p0;
    int pend4 = p0 + ((p1 - p0) & ~3);
    for (; p < pend4; p += 4) {
        int s0 = csr_src[p], s1 = csr_src[p + 1], s2 = csr_src[p + 2], s3 = csr_src[p + 3];
        float w0 = csr_w[p], w1 = csr_w[p + 1], w2 = csr_w[p + 2], w3 = csr_w[p + 3];
        H8 v0, v1, v2, v3;
        v0.f4 = *(const float4*)(h16 + (size_t)s0 * 512 + ch);
        v1.f4 = *(const float4*)(h16 + (size_t)s1 * 512 + ch);
        v2.f4 = *(const float4*)(h16 + (size_t)s2 * 512 + ch);
        v3.f4 = *(const float4*)(h16 + (size_t)s3 * 512 + ch);
#pragma unroll
        for (int j = 0; j < 4; j++) {
            float2 c0 = __half22float2(v0.h2[j]);
            float2 c1 = __half22float2(v1.h2[j]);
            float2 c2 = __half22float2(v2.h2[j]);
            float2 c3 = __half22float2(v3.h2[j]);
            a[2 * j] += w0 * c0.x + w1 * c1.x + w2 * c2.x + w3 * c3.x;
            a[2 * j + 1] += w0 * c0.y + w1 * c1.y + w2 * c2.y + w3 * c3.y;
        }
    }
    for (; p < p1; p++) {
        int s = csr_src[p];
        float wg = csr_w[p];
        H8 v;
        v.f4 = *(const float4*)(h16 + (size_t)s * 512 + ch);
#pragma unroll
        for (int j = 0; j < 4; j++) {
            float2 c = __half22float2(v.h2[j]);
            a[2 * j] += wg * c.x;
            a[2 * j + 1] += wg * c.y;
        }
    }

    float di = dinv[node];
    float wself = di * di;
    float4 hs0 = *(const float4*)(h32 + (size_t)node * 512 + ch);
    float4 hs1 = *(const float4*)(h32 + (size_t)node * 512 + ch + 4);
    float4 bv0 = *(const float4*)(bias + ch);
    float4 bv1 = *(const float4*)(bias + ch + 4);
    float s[8] = {hs0.x, hs0.y, hs0.z, hs0.w, hs1.x, hs1.y, hs1.z, hs1.w};
    float b[8] = {bv0.x, bv0.y, bv0.z, bv0.w, bv1.x, bv1.y, bv1.z, bv1.w};

    unsigned short hi[8], lo[8];
#pragma unroll
    for (int j = 0; j < 8; j++) {
        float v = gelu_tanh(a[j] + wself * s[j] + b[j]);
        hi[j] = bf16_rn(v);
        lo[j] = bf16_rn(v - bf16_f32(hi[j]));
    }
    *(ushort4*)(arow + ch) = make_ushort4(hi[0], hi[1], hi[2], hi[3]);
    *(ushort4*)(arow + ch + 4) = make_ushort4(hi[4], hi[5], hi[6], hi[7]);
    *(ushort4*)(arow + 512 + ch) = make_ushort4(lo[0], lo[1], lo[2], lo[3]);
    *(ushort4*)(arow + 512 + ch + 4) = make_ushort4(lo[4], lo[5], lo[6], lo[7]);
}

// Final agg: 256 ch, one wave per node (64 lanes x 4 fp16 ch), 4 nodes/block.
__global__ __launch_bounds__(256) void aggregate_final_kernel(
    const float* __restrict__ h32, const __half* __restrict__ h16,
    const int* __restrict__ offsets, const int* __restrict__ csr_src,
    const float* __restrict__ csr_w, const float* __restrict__ dinv,
    const float* __restrict__ bias, float* __restrict__ out) {
    int t = threadIdx.x;
    int node = __builtin_amdgcn_readfirstlane(blockIdx.x * 4 + (t >> 6));
    if (node >= N_NODES) return;
    int ch = (t & 63) * 4;
    int p0 = offsets[node], p1 = offsets[node + 1];
    float ax = 0.f, ay = 0.f, az = 0.f, aw = 0.f;

    union H4 { float2 f2; __half2 h2[2]; };
    int p = p0;
    int pend4 = p0 + ((p1 - p0) & ~3);
    for (; p < pend4; p += 4) {
        int s0 = csr_src[p], s1 = csr_src[p + 1], s2 = csr_src[p + 2], s3 = csr_src[p + 3];
        float w0 = csr_w[p], w1 = csr_w[p + 1], w2 = csr_w[p + 2], w3 = csr_w[p + 3];
        H4 v0, v1, v2, v3;
        v0.f2 = *(const float2*)(h16 + (size_t)s0 * 256 + ch);
        v1.f2 = *(const float2*)(h16 + (size_t)s1 * 256 + ch);
        v2.f2 = *(const float2*)(h16 + (size_t)s2 * 256 + ch);
        v3.f2 = *(const float2*)(h16 + (size_t)s3 * 256 + ch);
        float2 c00 = __half22float2(v0.h2[0]), c01 = __half22float2(v0.h2[1]);
        float2 c10 = __half22float2(v1.h2[0]), c11 = __half22float2(v1.h2[1]);
        float2 c20 = __half22float2(v2.h2[0]), c21 = __half22float2(v2.h2[1]);
        float2 c30 = __half22float2(v3.h2[0]), c31 = __half22float2(v3.h2[1]);
        ax += w0 * c00.x + w1 * c10.x + w2 * c20.x + w3 * c30.x;
        ay += w0 * c00.y + w1 * c10.y + w2 * c20.y + w3 * c30.y;
        az += w0 * c01.x + w1 * c11.x + w2 * c21.x + w3 * c31.x;
        aw += w0 * c01.y + w1 * c11.y + w2 * c21.y + w3 * c31.y;
    }
    for (; p < p1; p++) {
        int s = csr_src[p];
        float wg = csr_w[p];
        H4 v;
        v.f2 = *(const float2*)(h16 + (size_t)s * 256 + ch);
        float2 c0 = __half22float2(v.h2[0]), c1 = __half22float2(v.h2[1]);
        ax += wg * c0.x; ay += wg * c0.y; az += wg * c1.x; aw += wg * c1.y;
    }

    float di = dinv[node];
    float wself = di * di;
    float4 hs = *(const float4*)(h32 + (size_t)node * 256 + ch);
    float4 bv = *(const float4*)(bias + ch);
    float4 o = make_float4(ax + wself * hs.x + bv.x, ay + wself * hs.y + bv.y,
                           az + wself * hs.z + bv.z, aw + wself * hs.w + bv.w);
    *(float4*)(out + (size_t)node * 256 + ch) = o;
}

// ---------------- launch ----------------

static inline char* align16(char* p) { return (char*)(((size_t)p + 15) & ~(size_t)15); }

extern "C" void kernel_launch(void* const* d_in, const int* in_sizes, int n_in,
                              void* d_out, int out_size, void* d_ws, size_t ws_size,
                              hipStream_t stream) {
    const float* x  = (const float*)d_in[0];
    const int* eidx = (const int*)d_in[1];
    const float* W1 = (const float*)d_in[2];
    const float* b1 = (const float*)d_in[3];
    const float* W2 = (const float*)d_in[4];
    const float* b2 = (const float*)d_in[5];
    const float* W3 = (const float*)d_in[6];
    const float* b3 = (const float*)d_in[7];
    float* out = (float*)d_out;

    const int* src = eidx;
    const int* dst = eidx + N_EDGES;

    char* ws = (char*)d_ws;
    unsigned short* A2 = (unsigned short*)ws;  ws += (size_t)MPAD * KPHYS * 2;   // 102.5 MB
    float* Cbuf = (float*)ws;                  ws += (size_t)MPAD * 512 * 4;      // 102.5 MB
    __half* C16 = (__half*)ws;                 ws += (size_t)MPAD * 512 * 2;      // 51.2 MB
    unsigned short* B2T1 = (unsigned short*)ws; ws += (size_t)512 * KVIRT * 2;
    unsigned short* B2T2 = (unsigned short*)ws; ws += (size_t)512 * KVIRT * 2;
    unsigned short* B2T3 = (unsigned short*)ws; ws += (size_t)256 * KVIRT * 2;
    int* deg = (int*)ws;        ws = align16(ws + (size_t)N_NODES * 4);
    float* dinv = (float*)ws;   ws = align16(ws + (size_t)N_NODES * 4);
    int* offsets = (int*)ws;    ws = align16(ws + (size_t)(N_NODES + 1) * 4);
    int* cursor = (int*)ws;     ws = align16(ws + (size_t)N_NODES * 4);
    int* csr_src = (int*)ws;    ws = align16(ws + (size_t)N_EDGES * 4);
    float* csr_w = (float*)ws;  ws = align16(ws + (size_t)N_EDGES * 4);

    // ---- CSR build ----
    zero_int_kernel<<<(N_NODES + 255) / 256, 256, 0, stream>>>(deg, N_NODES);
    count_deg_kernel<<<(N_EDGES + 255) / 256, 256, 0, stream>>>(dst, deg);
    dinv_kernel<<<(N_NODES + 255) / 256, 256, 0, stream>>>(deg, dinv);
    scan_kernel<<<1, 1024, 0, stream>>>(deg, offsets, cursor);
    fill_csr_kernel<<<(N_EDGES + 255) / 256, 256, 0, stream>>>(src, dst, cursor, csr_src, csr_w, dinv);

    // ---- weight + input splits ----
    wsplit_kernel<<<(512 * 512 + 255) / 256, 256, 0, stream>>>(W1, B2T1, 512);
    wsplit_kernel<<<(512 * 512 + 255) / 256, 256, 0, stream>>>(W2, B2T2, 512);
    wsplit_kernel<<<(512 * 256 + 255) / 256, 256, 0, stream>>>(W3, B2T3, 256);
    split_x_kernel<<<MPAD, 256, 0, stream>>>(x, A2);

    // ---- layer 1 ----
    {
        dim3 grid(MPAD / 128, 512 / 128);
        gemm_split_bt<<<grid, 256, 0, stream>>>(A2, B2T1, Cbuf, C16, 512);
        aggregate_split_kernel<<<MPAD / 4, 256, 0, stream>>>(Cbuf, C16, offsets, csr_src, csr_w, dinv, b1, A2);
    }
    // ---- layer 2 ----
    {
        dim3 grid(MPAD / 128, 512 / 128);
        gemm_split_bt<<<grid, 256, 0, stream>>>(A2, B2T2, Cbuf, C16, 512);
        aggregate_split_kernel<<<MPAD / 4, 256, 0, stream>>>(Cbuf, C16, offsets, csr_src, csr_w, dinv, b2, A2);
    }
    // ---- layer 3 ----
    {
        dim3 grid(MPAD / 128, 256 / 128);
        gemm_split_bt<<<grid, 256, 0, stream>>>(A2, B2T3, Cbuf, C16, 256);
        aggregate_final_kernel<<<MPAD / 4, 256, 0, stream>>>(Cbuf, C16, offsets, csr_src, csr_w, dinv, b3, out);
    }
}

// Round 7
// 1111.493 us; speedup vs baseline: 1.1117x; 1.1117x over previous
//
#include <hip/hip_runtime.h>
#include <hip/hip_fp16.h>
#include <math.h>

#define N_NODES 50000
#define N_EDGES 800000
#define MPAD 50048            // 391 * 128, so GEMM needs no M bounds checks
#define KPHYS 1024            // A2 physical row width: [hi(512) | lo(512)]
#define KVIRT 1536            // virtual K: hi*hi + lo*hi + hi*lo

// ---------------- bf16 helpers ----------------

__device__ __forceinline__ unsigned short bf16_rn(float f) {
    unsigned u = __float_as_uint(f);
    u += 0x7FFFu + ((u >> 16) & 1u);  // round-to-nearest-even
    return (unsigned short)(u >> 16);
}
__device__ __forceinline__ float bf16_f32(unsigned short h) {
    return __uint_as_float(((unsigned)h) << 16);
}

// ---------------- degree / CSR build ----------------

__global__ void zero_int_kernel(int* __restrict__ p, int n) {
    int i = blockIdx.x * blockDim.x + threadIdx.x;
    if (i < n) p[i] = 0;
}

__global__ void count_deg_kernel(const int* __restrict__ dst, int* __restrict__ deg) {
    int e = blockIdx.x * blockDim.x + threadIdx.x;
    if (e < N_EDGES) atomicAdd(&deg[dst[e]], 1);
}

__global__ void dinv_kernel(const int* __restrict__ deg, float* __restrict__ dinv) {
    int i = blockIdx.x * blockDim.x + threadIdx.x;
    if (i < N_NODES) dinv[i] = rsqrtf((float)deg[i] + 1.0f);  // +1 self-loop
}

__global__ __launch_bounds__(1024) void scan_kernel(const int* __restrict__ deg,
                                                    int* __restrict__ offsets,
                                                    int* __restrict__ cursor) {
    __shared__ int sm[1024];
    int t = threadIdx.x;
    int base = 0;
    if (t == 0) offsets[0] = 0;
    for (int start = 0; start < N_NODES; start += 1024) {
        int i = start + t;
        int v = (i < N_NODES) ? deg[i] : 0;
        sm[t] = v;
        __syncthreads();
        for (int off = 1; off < 1024; off <<= 1) {
            int x = (t >= off) ? sm[t - off] : 0;
            __syncthreads();
            sm[t] += x;
            __syncthreads();
        }
        if (i < N_NODES) {
            offsets[i + 1] = base + sm[t];
            cursor[i] = base + sm[t] - v;
        }
        base += sm[1023];
        __syncthreads();
    }
}

__global__ void fill_csr_kernel(const int* __restrict__ src, const int* __restrict__ dst,
                                int* __restrict__ cursor, int* __restrict__ csr_src,
                                float* __restrict__ csr_w, const float* __restrict__ dinv) {
    int e = blockIdx.x * blockDim.x + threadIdx.x;
    if (e < N_EDGES) {
        int s = src[e], d = dst[e];
        int p = atomicAdd(&cursor[d], 1);
        csr_src[p] = s;
        csr_w[p] = dinv[s] * dinv[d];
    }
}

// ---------------- split-bf16 MFMA GEMM (+ fp16 mirror output) ----------------
// Staging keeps R5's coalesced row-order (4 consecutive lanes = one 64B row
// segment) but XOR-swizzles the k-chunk slot within each row:
//   thread t stages (row = t>>2, kc = (t&3) ^ ((t>>3)&3)) into LDS chunk t.
// Read side: (row, kc) lives at chunk row*4 + (kc ^ ((row>>1)&3)), so the
// b128 fragment reads hit all 32 banks evenly (2-way = free) instead of
// R5's 8-bank pileup (9.6M conflicts).

typedef __attribute__((ext_vector_type(8))) short bf16x8;
typedef __attribute__((ext_vector_type(4))) float floatx4;

#define GLL16(g, l)                                                                   \
    __builtin_amdgcn_global_load_lds((__attribute__((address_space(1))) const void*)(g), \
                                     (__attribute__((address_space(3))) void*)(l), 16, 0, 0)

__global__ __launch_bounds__(256) void gemm_split_bt(const unsigned short* __restrict__ A2,
                                                     const unsigned short* __restrict__ B2T,
                                                     float* __restrict__ C,
                                                     __half* __restrict__ C16, int N) {
    __shared__ unsigned short As[128 * 32];  // 128 rows x 4 swizzled 16B chunks
    __shared__ unsigned short Bs[128 * 32];

    const int t = threadIdx.x;
    const int lane = t & 63;
    const int quad = lane >> 4;
    const int l15 = lane & 15;
    const int w = t >> 6;
    const int wm = w & 1, wn = w >> 1;
    const int row0 = blockIdx.x * 128;
    const int col0 = blockIdx.y * 128;

    floatx4 acc[4][4];
#pragma unroll
    for (int i = 0; i < 4; i++)
#pragma unroll
        for (int j = 0; j < 4; j++) acc[i][j] = (floatx4){0.f, 0.f, 0.f, 0.f};

    // coalesced staging with XOR-swizzled k-chunk
    const int sr = t >> 2;
    const int skc = (t & 3) ^ ((t >> 3) & 3);
    const int sk = skc * 8;
    const unsigned short* Arow0 = A2 + (size_t)(row0 + sr) * KPHYS + sk;
    const unsigned short* Arow1 = Arow0 + (size_t)64 * KPHYS;
    const unsigned short* Brow0 = B2T + (size_t)(col0 + sr) * KVIRT + sk;
    const unsigned short* Brow1 = Brow0 + (size_t)64 * KVIRT;
    unsigned short* lA0 = As + t * 8;
    unsigned short* lA1 = As + 2048 + t * 8;
    unsigned short* lB0 = Bs + t * 8;
    unsigned short* lB1 = Bs + 2048 + t * 8;

    // fragment-read swizzle: chunk column = quad ^ ((row>>1)&3); row ≡ l15 (mod 16)
    const int fcol = (quad ^ ((l15 >> 1) & 3)) * 8;

    for (int kb = 0; kb < KVIRT; kb += 32) {
        const int kA = (kb < KPHYS) ? kb : kb - KPHYS;  // virtual hi-replay wraps onto physical hi
        __syncthreads();
        GLL16(Arow0 + kA, lA0);
        GLL16(Arow1 + kA, lA1);
        GLL16(Brow0 + kb, lB0);
        GLL16(Brow1 + kb, lB1);
        __syncthreads();

        bf16x8 af[4], bf[4];
#pragma unroll
        for (int mt = 0; mt < 4; mt++)
            af[mt] = *(const bf16x8*)(As + (wm * 64 + mt * 16 + l15) * 32 + fcol);
#pragma unroll
        for (int nt = 0; nt < 4; nt++)
            bf[nt] = *(const bf16x8*)(Bs + (wn * 64 + nt * 16 + l15) * 32 + fcol);
#pragma unroll
        for (int mt = 0; mt < 4; mt++)
#pragma unroll
            for (int nt = 0; nt < 4; nt++)
                acc[mt][nt] = __builtin_amdgcn_mfma_f32_16x16x32_bf16(af[mt], bf[nt], acc[mt][nt], 0, 0, 0);
    }

#pragma unroll
    for (int mt = 0; mt < 4; mt++) {
#pragma unroll
        for (int r = 0; r < 4; r++) {
            int row = row0 + wm * 64 + mt * 16 + quad * 4 + r;
            float* Cp = C + (size_t)row * N + col0 + wn * 64 + l15;
            __half* Cp16 = C16 + (size_t)row * N + col0 + wn * 64 + l15;
#pragma unroll
            for (int nt = 0; nt < 4; nt++) {
                Cp[nt * 16] = acc[mt][nt][r];
                Cp16[nt * 16] = __float2half(acc[mt][nt][r]);
            }
        }
    }
}

// ---------------- weight split (W [K x N] fp32 -> B2T [N x KVIRT] bf16) ----------------

__global__ void wsplit_kernel(const float* __restrict__ W, unsigned short* __restrict__ B2T, int N) {
    int idx = blockIdx.x * blockDim.x + threadIdx.x;
    if (idx >= 512 * N) return;
    int k = idx / N, n = idx % N;
    float v = W[(size_t)k * N + n];
    unsigned short hi = bf16_rn(v);
    unsigned short lo = bf16_rn(v - bf16_f32(hi));
    unsigned short* row = B2T + (size_t)n * KVIRT;
    row[k] = hi;
    row[512 + k] = hi;
    row[1024 + k] = lo;
}

// ---------------- x split (fp32 [N_NODES x 512] -> A2 [MPAD x KPHYS]) ----------------

__global__ __launch_bounds__(256) void split_x_kernel(const float* __restrict__ x,
                                                      unsigned short* __restrict__ A2) {
    int m = blockIdx.x;
    int ch = threadIdx.x * 2;
    unsigned short* arow = A2 + (size_t)m * KPHYS;
    float vx = 0.f, vy = 0.f;
    if (m < N_NODES) {
        float2 v = *(const float2*)(x + (size_t)m * 512 + ch);
        vx = v.x;
        vy = v.y;
    }
    unsigned short hx = bf16_rn(vx), hy = bf16_rn(vy);
    arow[ch] = hx;
    arow[ch + 1] = hy;
    arow[512 + ch] = bf16_rn(vx - bf16_f32(hx));
    arow[512 + ch + 1] = bf16_rn(vy - bf16_f32(hy));
}

// ---------------- aggregation ----------------

__device__ __forceinline__ float gelu_tanh(float x) {
    float x3 = x * x * x;
    float inner = 0.7978845608028654f * (x + 0.044715f * x3);
    return 0.5f * x * (1.0f + tanhf(inner));
}

// One wave per node: 64 lanes x 8 fp16 ch = 512 ch. 4 nodes per 256-thread block.
__global__ __launch_bounds__(256) void aggregate_split_kernel(
    const float* __restrict__ h32, const __half* __restrict__ h16,
    const int* __restrict__ offsets, const int* __restrict__ csr_src,
    const float* __restrict__ csr_w, const float* __restrict__ dinv,
    const float* __restrict__ bias, unsigned short* __restrict__ A2) {
    int t = threadIdx.x;
    int node = __builtin_amdgcn_readfirstlane(blockIdx.x * 4 + (t >> 6));
    int ch = (t & 63) * 8;
    unsigned short* arow = A2 + (size_t)node * KPHYS;
    if (node >= N_NODES) {  // zero pad rows (16B per store)
        *(uint4*)(arow + ch) = make_uint4(0, 0, 0, 0);
        *(uint4*)(arow + 512 + ch) = make_uint4(0, 0, 0, 0);
        return;
    }
    int p0 = offsets[node], p1 = offsets[node + 1];
    float a[8] = {0.f, 0.f, 0.f, 0.f, 0.f, 0.f, 0.f, 0.f};

    union H8 { float4 f4; __half2 h2[4]; };
    int p = p0;
    int pend4 = p0 + ((p1 - p0) & ~3);
    for (; p < pend4; p += 4) {
        int s0 = csr_src[p], s1 = csr_src[p + 1], s2 = csr_src[p + 2], s3 = csr_src[p + 3];
        float w0 = csr_w[p], w1 = csr_w[p + 1], w2 = csr_w[p + 2], w3 = csr_w[p + 3];
        H8 v0, v1, v2, v3;
        v0.f4 = *(const float4*)(h16 + (size_t)s0 * 512 + ch);
        v1.f4 = *(const float4*)(h16 + (size_t)s1 * 512 + ch);
        v2.f4 = *(const float4*)(h16 + (size_t)s2 * 512 + ch);
        v3.f4 = *(const float4*)(h16 + (size_t)s3 * 512 + ch);
#pragma unroll
        for (int j = 0; j < 4; j++) {
            float2 c0 = __half22float2(v0.h2[j]);
            float2 c1 = __half22float2(v1.h2[j]);
            float2 c2 = __half22float2(v2.h2[j]);
            float2 c3 = __half22float2(v3.h2[j]);
            a[2 * j] += w0 * c0.x + w1 * c1.x + w2 * c2.x + w3 * c3.x;
            a[2 * j + 1] += w0 * c0.y + w1 * c1.y + w2 * c2.y + w3 * c3.y;
        }
    }
    for (; p < p1; p++) {
        int s = csr_src[p];
        float wg = csr_w[p];
        H8 v;
        v.f4 = *(const float4*)(h16 + (size_t)s * 512 + ch);
#pragma unroll
        for (int j = 0; j < 4; j++) {
            float2 c = __half22float2(v.h2[j]);
            a[2 * j] += wg * c.x;
            a[2 * j + 1] += wg * c.y;
        }
    }

    float di = dinv[node];
    float wself = di * di;
    float4 hs0 = *(const float4*)(h32 + (size_t)node * 512 + ch);
    float4 hs1 = *(const float4*)(h32 + (size_t)node * 512 + ch + 4);
    float4 bv0 = *(const float4*)(bias + ch);
    float4 bv1 = *(const float4*)(bias + ch + 4);
    float s[8] = {hs0.x, hs0.y, hs0.z, hs0.w, hs1.x, hs1.y, hs1.z, hs1.w};
    float b[8] = {bv0.x, bv0.y, bv0.z, bv0.w, bv1.x, bv1.y, bv1.z, bv1.w};

    unsigned short hi[8], lo[8];
#pragma unroll
    for (int j = 0; j < 8; j++) {
        float v = gelu_tanh(a[j] + wself * s[j] + b[j]);
        hi[j] = bf16_rn(v);
        lo[j] = bf16_rn(v - bf16_f32(hi[j]));
    }
    *(ushort4*)(arow + ch) = make_ushort4(hi[0], hi[1], hi[2], hi[3]);
    *(ushort4*)(arow + ch + 4) = make_ushort4(hi[4], hi[5], hi[6], hi[7]);
    *(ushort4*)(arow + 512 + ch) = make_ushort4(lo[0], lo[1], lo[2], lo[3]);
    *(ushort4*)(arow + 512 + ch + 4) = make_ushort4(lo[4], lo[5], lo[6], lo[7]);
}

// Final agg: 256 ch, one wave per node (64 lanes x 4 fp16 ch), 4 nodes/block.
__global__ __launch_bounds__(256) void aggregate_final_kernel(
    const float* __restrict__ h32, const __half* __restrict__ h16,
    const int* __restrict__ offsets, const int* __restrict__ csr_src,
    const float* __restrict__ csr_w, const float* __restrict__ dinv,
    const float* __restrict__ bias, float* __restrict__ out) {
    int t = threadIdx.x;
    int node = __builtin_amdgcn_readfirstlane(blockIdx.x * 4 + (t >> 6));
    if (node >= N_NODES) return;
    int ch = (t & 63) * 4;
    int p0 = offsets[node], p1 = offsets[node + 1];
    float ax = 0.f, ay = 0.f, az = 0.f, aw = 0.f;

    union H4 { float2 f2; __half2 h2[2]; };
    int p = p0;
    int pend4 = p0 + ((p1 - p0) & ~3);
    for (; p < pend4; p += 4) {
        int s0 = csr_src[p], s1 = csr_src[p + 1], s2 = csr_src[p + 2], s3 = csr_src[p + 3];
        float w0 = csr_w[p], w1 = csr_w[p + 1], w2 = csr_w[p + 2], w3 = csr_w[p + 3];
        H4 v0, v1, v2, v3;
        v0.f2 = *(const float2*)(h16 + (size_t)s0 * 256 + ch);
        v1.f2 = *(const float2*)(h16 + (size_t)s1 * 256 + ch);
        v2.f2 = *(const float2*)(h16 + (size_t)s2 * 256 + ch);
        v3.f2 = *(const float2*)(h16 + (size_t)s3 * 256 + ch);
        float2 c00 = __half22float2(v0.h2[0]), c01 = __half22float2(v0.h2[1]);
        float2 c10 = __half22float2(v1.h2[0]), c11 = __half22float2(v1.h2[1]);
        float2 c20 = __half22float2(v2.h2[0]), c21 = __half22float2(v2.h2[1]);
        float2 c30 = __half22float2(v3.h2[0]), c31 = __half22float2(v3.h2[1]);
        ax += w0 * c00.x + w1 * c10.x + w2 * c20.x + w3 * c30.x;
        ay += w0 * c00.y + w1 * c10.y + w2 * c20.y + w3 * c30.y;
        az += w0 * c01.x + w1 * c11.x + w2 * c21.x + w3 * c31.x;
        aw += w0 * c01.y + w1 * c11.y + w2 * c21.y + w3 * c31.y;
    }
    for (; p < p1; p++) {
        int s = csr_src[p];
        float wg = csr_w[p];
        H4 v;
        v.f2 = *(const float2*)(h16 + (size_t)s * 256 + ch);
        float2 c0 = __half22float2(v.h2[0]), c1 = __half22float2(v.h2[1]);
        ax += wg * c0.x; ay += wg * c0.y; az += wg * c1.x; aw += wg * c1.y;
    }

    float di = dinv[node];
    float wself = di * di;
    float4 hs = *(const float4*)(h32 + (size_t)node * 256 + ch);
    float4 bv = *(const float4*)(bias + ch);
    float4 o = make_float4(ax + wself * hs.x + bv.x, ay + wself * hs.y + bv.y,
                           az + wself * hs.z + bv.z, aw + wself * hs.w + bv.w);
    *(float4*)(out + (size_t)node * 256 + ch) = o;
}

// ---------------- launch ----------------

static inline char* align16(char* p) { return (char*)(((size_t)p + 15) & ~(size_t)15); }

extern "C" void kernel_launch(void* const* d_in, const int* in_sizes, int n_in,
                              void* d_out, int out_size, void* d_ws, size_t ws_size,
                              hipStream_t stream) {
    const float* x  = (const float*)d_in[0];
    const int* eidx = (const int*)d_in[1];
    const float* W1 = (const float*)d_in[2];
    const float* b1 = (const float*)d_in[3];
    const float* W2 = (const float*)d_in[4];
    const float* b2 = (const float*)d_in[5];
    const float* W3 = (const float*)d_in[6];
    const float* b3 = (const float*)d_in[7];
    float* out = (float*)d_out;

    const int* src = eidx;
    const int* dst = eidx + N_EDGES;

    char* ws = (char*)d_ws;
    unsigned short* A2 = (unsigned short*)ws;  ws += (size_t)MPAD * KPHYS * 2;   // 102.5 MB
    float* Cbuf = (float*)ws;                  ws += (size_t)MPAD * 512 * 4;      // 102.5 MB
    __half* C16 = (__half*)ws;                 ws += (size_t)MPAD * 512 * 2;      // 51.2 MB
    unsigned short* B2T1 = (unsigned short*)ws; ws += (size_t)512 * KVIRT * 2;
    unsigned short* B2T2 = (unsigned short*)ws; ws += (size_t)512 * KVIRT * 2;
    unsigned short* B2T3 = (unsigned short*)ws; ws += (size_t)256 * KVIRT * 2;
    int* deg = (int*)ws;        ws = align16(ws + (size_t)N_NODES * 4);
    float* dinv = (float*)ws;   ws = align16(ws + (size_t)N_NODES * 4);
    int* offsets = (int*)ws;    ws = align16(ws + (size_t)(N_NODES + 1) * 4);
    int* cursor = (int*)ws;     ws = align16(ws + (size_t)N_NODES * 4);
    int* csr_src = (int*)ws;    ws = align16(ws + (size_t)N_EDGES * 4);
    float* csr_w = (float*)ws;  ws = align16(ws + (size_t)N_EDGES * 4);

    // ---- CSR build ----
    zero_int_kernel<<<(N_NODES + 255) / 256, 256, 0, stream>>>(deg, N_NODES);
    count_deg_kernel<<<(N_EDGES + 255) / 256, 256, 0, stream>>>(dst, deg);
    dinv_kernel<<<(N_NODES + 255) / 256, 256, 0, stream>>>(deg, dinv);
    scan_kernel<<<1, 1024, 0, stream>>>(deg, offsets, cursor);
    fill_csr_kernel<<<(N_EDGES + 255) / 256, 256, 0, stream>>>(src, dst, cursor, csr_src, csr_w, dinv);

    // ---- weight + input splits ----
    wsplit_kernel<<<(512 * 512 + 255) / 256, 256, 0, stream>>>(W1, B2T1, 512);
    wsplit_kernel<<<(512 * 512 + 255) / 256, 256, 0, stream>>>(W2, B2T2, 512);
    wsplit_kernel<<<(512 * 256 + 255) / 256, 256, 0, stream>>>(W3, B2T3, 256);
    split_x_kernel<<<MPAD, 256, 0, stream>>>(x, A2);

    // ---- layer 1 ----
    {
        dim3 grid(MPAD / 128, 512 / 128);
        gemm_split_bt<<<grid, 256, 0, stream>>>(A2, B2T1, Cbuf, C16, 512);
        aggregate_split_kernel<<<MPAD / 4, 256, 0, stream>>>(Cbuf, C16, offsets, csr_src, csr_w, dinv, b1, A2);
    }
    // ---- layer 2 ----
    {
        dim3 grid(MPAD / 128, 512 / 128);
        gemm_split_bt<<<grid, 256, 0, stream>>>(A2, B2T2, Cbuf, C16, 512);
        aggregate_split_kernel<<<MPAD / 4, 256, 0, stream>>>(Cbuf, C16, offsets, csr_src, csr_w, dinv, b2, A2);
    }
    // ---- layer 3 ----
    {
        dim3 grid(MPAD / 128, 256 / 128);
        gemm_split_bt<<<grid, 256, 0, stream>>>(A2, B2T3, Cbuf, C16, 256);
        aggregate_final_kernel<<<MPAD / 4, 256, 0, stream>>>(Cbuf, C16, offsets, csr_src, csr_w, dinv, b3, out);
    }
}

// Round 8
// 1092.885 us; speedup vs baseline: 1.1307x; 1.0170x over previous
//
#include <hip/hip_runtime.h>
#include <hip/hip_fp16.h>
#include <math.h>

#define N_NODES 50000
#define N_EDGES 800000
#define MPAD 50048            // 391 * 128, so GEMM needs no M bounds checks
#define KPHYS 1024            // A2 physical row width: [hi(512) | lo(512)]
#define KVIRT 1536            // virtual K: hi*hi + lo*hi + hi*lo
#define NKITER (KVIRT / 32)   // 48

// ---------------- bf16 helpers ----------------

__device__ __forceinline__ unsigned short bf16_rn(float f) {
    unsigned u = __float_as_uint(f);
    u += 0x7FFFu + ((u >> 16) & 1u);  // round-to-nearest-even
    return (unsigned short)(u >> 16);
}
__device__ __forceinline__ float bf16_f32(unsigned short h) {
    return __uint_as_float(((unsigned)h) << 16);
}

// ---------------- degree / CSR build ----------------

__global__ void zero_int_kernel(int* __restrict__ p, int n) {
    int i = blockIdx.x * blockDim.x + threadIdx.x;
    if (i < n) p[i] = 0;
}

__global__ void count_deg_kernel(const int* __restrict__ dst, int* __restrict__ deg) {
    int e = blockIdx.x * blockDim.x + threadIdx.x;
    if (e < N_EDGES) atomicAdd(&deg[dst[e]], 1);
}

__global__ void dinv_kernel(const int* __restrict__ deg, float* __restrict__ dinv) {
    int i = blockIdx.x * blockDim.x + threadIdx.x;
    if (i < N_NODES) dinv[i] = rsqrtf((float)deg[i] + 1.0f);  // +1 self-loop
}

__global__ __launch_bounds__(1024) void scan_kernel(const int* __restrict__ deg,
                                                    int* __restrict__ offsets,
                                                    int* __restrict__ cursor) {
    __shared__ int sm[1024];
    int t = threadIdx.x;
    int base = 0;
    if (t == 0) offsets[0] = 0;
    for (int start = 0; start < N_NODES; start += 1024) {
        int i = start + t;
        int v = (i < N_NODES) ? deg[i] : 0;
        sm[t] = v;
        __syncthreads();
        for (int off = 1; off < 1024; off <<= 1) {
            int x = (t >= off) ? sm[t - off] : 0;
            __syncthreads();
            sm[t] += x;
            __syncthreads();
        }
        if (i < N_NODES) {
            offsets[i + 1] = base + sm[t];
            cursor[i] = base + sm[t] - v;
        }
        base += sm[1023];
        __syncthreads();
    }
}

__global__ void fill_csr_kernel(const int* __restrict__ src, const int* __restrict__ dst,
                                int* __restrict__ cursor, int* __restrict__ csr_src,
                                float* __restrict__ csr_w, const float* __restrict__ dinv) {
    int e = blockIdx.x * blockDim.x + threadIdx.x;
    if (e < N_EDGES) {
        int s = src[e], d = dst[e];
        int p = atomicAdd(&cursor[d], 1);
        csr_src[p] = s;
        csr_w[p] = dinv[s] * dinv[d];
    }
}

// ---------------- split-bf16 MFMA GEMM (+ fp16 mirror output) ----------------
// R7's XOR-swizzled staging (coalesced + conflict-free) + explicit LDS
// double-buffer: prefetch tile k+1 into the alternate buffer BEFORE computing
// tile k, one barrier per iteration, so the staging latency overlaps MFMA.
// Grid is (col, row) so co-dispatched blocks share the A row-band (L2/L3 reuse).

typedef __attribute__((ext_vector_type(8))) short bf16x8;
typedef __attribute__((ext_vector_type(4))) float floatx4;

#define GLL16(g, l)                                                                   \
    __builtin_amdgcn_global_load_lds((__attribute__((address_space(1))) const void*)(g), \
                                     (__attribute__((address_space(3))) void*)(l), 16, 0, 0)

__global__ __launch_bounds__(256) void gemm_split_bt(const unsigned short* __restrict__ A2,
                                                     const unsigned short* __restrict__ B2T,
                                                     float* __restrict__ C,
                                                     __half* __restrict__ C16, int N) {
    __shared__ unsigned short As[2][128 * 32];  // double-buffered, swizzled chunks
    __shared__ unsigned short Bs[2][128 * 32];

    const int t = threadIdx.x;
    const int lane = t & 63;
    const int quad = lane >> 4;
    const int l15 = lane & 15;
    const int w = t >> 6;
    const int wm = w & 1, wn = w >> 1;
    const int row0 = blockIdx.y * 128;   // grid transposed: y = row band
    const int col0 = blockIdx.x * 128;   //                  x = col block

    floatx4 acc[4][4];
#pragma unroll
    for (int i = 0; i < 4; i++)
#pragma unroll
        for (int j = 0; j < 4; j++) acc[i][j] = (floatx4){0.f, 0.f, 0.f, 0.f};

    // coalesced staging with XOR-swizzled k-chunk (R7)
    const int sr = t >> 2;
    const int sk = ((t & 3) ^ ((t >> 3) & 3)) * 8;
    const unsigned short* Arow0 = A2 + (size_t)(row0 + sr) * KPHYS + sk;
    const unsigned short* Arow1 = Arow0 + (size_t)64 * KPHYS;
    const unsigned short* Brow0 = B2T + (size_t)(col0 + sr) * KVIRT + sk;
    const unsigned short* Brow1 = Brow0 + (size_t)64 * KVIRT;

    // fragment-read swizzle: chunk column = quad ^ ((l15>>1)&3)
    const int fcol = (quad ^ ((l15 >> 1) & 3)) * 8;

    // prologue: stage tile 0 into buffer 0
    {
        GLL16(Arow0 + 0, As[0] + t * 8);
        GLL16(Arow1 + 0, As[0] + 2048 + t * 8);
        GLL16(Brow0 + 0, Bs[0] + t * 8);
        GLL16(Brow1 + 0, Bs[0] + 2048 + t * 8);
    }

    for (int it = 0; it < NKITER; it++) {
        const int cur = it & 1;
        __syncthreads();  // drains prefetch into cur; all reads of cur^1 done
        if (it + 1 < NKITER) {
            const int kbn = (it + 1) * 32;
            const int kAn = (kbn < KPHYS) ? kbn : kbn - KPHYS;
            const int nxt = cur ^ 1;
            GLL16(Arow0 + kAn, As[nxt] + t * 8);
            GLL16(Arow1 + kAn, As[nxt] + 2048 + t * 8);
            GLL16(Brow0 + kbn, Bs[nxt] + t * 8);
            GLL16(Brow1 + kbn, Bs[nxt] + 2048 + t * 8);
        }

        bf16x8 af[4], bf[4];
#pragma unroll
        for (int mt = 0; mt < 4; mt++)
            af[mt] = *(const bf16x8*)(As[cur] + (wm * 64 + mt * 16 + l15) * 32 + fcol);
#pragma unroll
        for (int nt = 0; nt < 4; nt++)
            bf[nt] = *(const bf16x8*)(Bs[cur] + (wn * 64 + nt * 16 + l15) * 32 + fcol);
#pragma unroll
        for (int mt = 0; mt < 4; mt++)
#pragma unroll
            for (int nt = 0; nt < 4; nt++)
                acc[mt][nt] = __builtin_amdgcn_mfma_f32_16x16x32_bf16(af[mt], bf[nt], acc[mt][nt], 0, 0, 0);
    }

#pragma unroll
    for (int mt = 0; mt < 4; mt++) {
#pragma unroll
        for (int r = 0; r < 4; r++) {
            int row = row0 + wm * 64 + mt * 16 + quad * 4 + r;
            float* Cp = C + (size_t)row * N + col0 + wn * 64 + l15;
            __half* Cp16 = C16 + (size_t)row * N + col0 + wn * 64 + l15;
#pragma unroll
            for (int nt = 0; nt < 4; nt++) {
                Cp[nt * 16] = acc[mt][nt][r];
                Cp16[nt * 16] = __float2half(acc[mt][nt][r]);
            }
        }
    }
}

// ---------------- weight split (W [K x N] fp32 -> B2T [N x KVIRT] bf16) ----------------

__global__ void wsplit_kernel(const float* __restrict__ W, unsigned short* __restrict__ B2T, int N) {
    int idx = blockIdx.x * blockDim.x + threadIdx.x;
    if (idx >= 512 * N) return;
    int k = idx / N, n = idx % N;
    float v = W[(size_t)k * N + n];
    unsigned short hi = bf16_rn(v);
    unsigned short lo = bf16_rn(v - bf16_f32(hi));
    unsigned short* row = B2T + (size_t)n * KVIRT;
    row[k] = hi;
    row[512 + k] = hi;
    row[1024 + k] = lo;
}

// ---------------- x split (fp32 [N_NODES x 512] -> A2 [MPAD x KPHYS]) ----------------

__global__ __launch_bounds__(256) void split_x_kernel(const float* __restrict__ x,
                                                      unsigned short* __restrict__ A2) {
    int m = blockIdx.x;
    int ch = threadIdx.x * 2;
    unsigned short* arow = A2 + (size_t)m * KPHYS;
    float vx = 0.f, vy = 0.f;
    if (m < N_NODES) {
        float2 v = *(const float2*)(x + (size_t)m * 512 + ch);
        vx = v.x;
        vy = v.y;
    }
    unsigned short hx = bf16_rn(vx), hy = bf16_rn(vy);
    arow[ch] = hx;
    arow[ch + 1] = hy;
    arow[512 + ch] = bf16_rn(vx - bf16_f32(hx));
    arow[512 + ch + 1] = bf16_rn(vy - bf16_f32(hy));
}

// ---------------- aggregation ----------------

__device__ __forceinline__ float gelu_tanh(float x) {
    float x3 = x * x * x;
    float inner = 0.7978845608028654f * (x + 0.044715f * x3);
    return 0.5f * x * (1.0f + tanhf(inner));
}

// One wave per node: 64 lanes x 8 fp16 ch = 512 ch. 4 nodes per 256-thread block.
__global__ __launch_bounds__(256) void aggregate_split_kernel(
    const float* __restrict__ h32, const __half* __restrict__ h16,
    const int* __restrict__ offsets, const int* __restrict__ csr_src,
    const float* __restrict__ csr_w, const float* __restrict__ dinv,
    const float* __restrict__ bias, unsigned short* __restrict__ A2) {
    int t = threadIdx.x;
    int node = __builtin_amdgcn_readfirstlane(blockIdx.x * 4 + (t >> 6));
    int ch = (t & 63) * 8;
    unsigned short* arow = A2 + (size_t)node * KPHYS;
    if (node >= N_NODES) {  // zero pad rows (16B per store)
        *(uint4*)(arow + ch) = make_uint4(0, 0, 0, 0);
        *(uint4*)(arow + 512 + ch) = make_uint4(0, 0, 0, 0);
        return;
    }
    int p0 = offsets[node], p1 = offsets[node + 1];
    float a[8] = {0.f, 0.f, 0.f, 0.f, 0.f, 0.f, 0.f, 0.f};

    union H8 { float4 f4; __half2 h2[4]; };
    int p = p0;
    int pend4 = p0 + ((p1 - p0) & ~3);
    for (; p < pend4; p += 4) {
        int s0 = csr_src[p], s1 = csr_src[p + 1], s2 = csr_src[p + 2], s3 = csr_src[p + 3];
        float w0 = csr_w[p], w1 = csr_w[p + 1], w2 = csr_w[p + 2], w3 = csr_w[p + 3];
        H8 v0, v1, v2, v3;
        v0.f4 = *(const float4*)(h16 + (size_t)s0 * 512 + ch);
        v1.f4 = *(const float4*)(h16 + (size_t)s1 * 512 + ch);
        v2.f4 = *(const float4*)(h16 + (size_t)s2 * 512 + ch);
        v3.f4 = *(const float4*)(h16 + (size_t)s3 * 512 + ch);
#pragma unroll
        for (int j = 0; j < 4; j++) {
            float2 c0 = __half22float2(v0.h2[j]);
            float2 c1 = __half22float2(v1.h2[j]);
            float2 c2 = __half22float2(v2.h2[j]);
            float2 c3 = __half22float2(v3.h2[j]);
            a[2 * j] += w0 * c0.x + w1 * c1.x + w2 * c2.x + w3 * c3.x;
            a[2 * j + 1] += w0 * c0.y + w1 * c1.y + w2 * c2.y + w3 * c3.y;
        }
    }
    for (; p < p1; p++) {
        int s = csr_src[p];
        float wg = csr_w[p];
        H8 v;
        v.f4 = *(const float4*)(h16 + (size_t)s * 512 + ch);
#pragma unroll
        for (int j = 0; j < 4; j++) {
            float2 c = __half22float2(v.h2[j]);
            a[2 * j] += wg * c.x;
            a[2 * j + 1] += wg * c.y;
        }
    }

    float di = dinv[node];
    float wself = di * di;
    float4 hs0 = *(const float4*)(h32 + (size_t)node * 512 + ch);
    float4 hs1 = *(const float4*)(h32 + (size_t)node * 512 + ch + 4);
    float4 bv0 = *(const float4*)(bias + ch);
    float4 bv1 = *(const float4*)(bias + ch + 4);
    float s[8] = {hs0.x, hs0.y, hs0.z, hs0.w, hs1.x, hs1.y, hs1.z, hs1.w};
    float b[8] = {bv0.x, bv0.y, bv0.z, bv0.w, bv1.x, bv1.y, bv1.z, bv1.w};

    unsigned short hi[8], lo[8];
#pragma unroll
    for (int j = 0; j < 8; j++) {
        float v = gelu_tanh(a[j] + wself * s[j] + b[j]);
        hi[j] = bf16_rn(v);
        lo[j] = bf16_rn(v - bf16_f32(hi[j]));
    }
    *(ushort4*)(arow + ch) = make_ushort4(hi[0], hi[1], hi[2], hi[3]);
    *(ushort4*)(arow + ch + 4) = make_ushort4(hi[4], hi[5], hi[6], hi[7]);
    *(ushort4*)(arow + 512 + ch) = make_ushort4(lo[0], lo[1], lo[2], lo[3]);
    *(ushort4*)(arow + 512 + ch + 4) = make_ushort4(lo[4], lo[5], lo[6], lo[7]);
}

// Final agg: 256 ch, one wave per node (64 lanes x 4 fp16 ch), 4 nodes/block.
__global__ __launch_bounds__(256) void aggregate_final_kernel(
    const float* __restrict__ h32, const __half* __restrict__ h16,
    const int* __restrict__ offsets, const int* __restrict__ csr_src,
    const float* __restrict__ csr_w, const float* __restrict__ dinv,
    const float* __restrict__ bias, float* __restrict__ out) {
    int t = threadIdx.x;
    int node = __builtin_amdgcn_readfirstlane(blockIdx.x * 4 + (t >> 6));
    if (node >= N_NODES) return;
    int ch = (t & 63) * 4;
    int p0 = offsets[node], p1 = offsets[node + 1];
    float ax = 0.f, ay = 0.f, az = 0.f, aw = 0.f;

    union H4 { float2 f2; __half2 h2[2]; };
    int p = p0;
    int pend4 = p0 + ((p1 - p0) & ~3);
    for (; p < pend4; p += 4) {
        int s0 = csr_src[p], s1 = csr_src[p + 1], s2 = csr_src[p + 2], s3 = csr_src[p + 3];
        float w0 = csr_w[p], w1 = csr_w[p + 1], w2 = csr_w[p + 2], w3 = csr_w[p + 3];
        H4 v0, v1, v2, v3;
        v0.f2 = *(const float2*)(h16 + (size_t)s0 * 256 + ch);
        v1.f2 = *(const float2*)(h16 + (size_t)s1 * 256 + ch);
        v2.f2 = *(const float2*)(h16 + (size_t)s2 * 256 + ch);
        v3.f2 = *(const float2*)(h16 + (size_t)s3 * 256 + ch);
        float2 c00 = __half22float2(v0.h2[0]), c01 = __half22float2(v0.h2[1]);
        float2 c10 = __half22float2(v1.h2[0]), c11 = __half22float2(v1.h2[1]);
        float2 c20 = __half22float2(v2.h2[0]), c21 = __half22float2(v2.h2[1]);
        float2 c30 = __half22float2(v3.h2[0]), c31 = __half22float2(v3.h2[1]);
        ax += w0 * c00.x + w1 * c10.x + w2 * c20.x + w3 * c30.x;
        ay += w0 * c00.y + w1 * c10.y + w2 * c20.y + w3 * c30.y;
        az += w0 * c01.x + w1 * c11.x + w2 * c21.x + w3 * c31.x;
        aw += w0 * c01.y + w1 * c11.y + w2 * c21.y + w3 * c31.y;
    }
    for (; p < p1; p++) {
        int s = csr_src[p];
        float wg = csr_w[p];
        H4 v;
        v.f2 = *(const float2*)(h16 + (size_t)s * 256 + ch);
        float2 c0 = __half22float2(v.h2[0]), c1 = __half22float2(v.h2[1]);
        ax += wg * c0.x; ay += wg * c0.y; az += wg * c1.x; aw += wg * c1.y;
    }

    float di = dinv[node];
    float wself = di * di;
    float4 hs = *(const float4*)(h32 + (size_t)node * 256 + ch);
    float4 bv = *(const float4*)(bias + ch);
    float4 o = make_float4(ax + wself * hs.x + bv.x, ay + wself * hs.y + bv.y,
                           az + wself * hs.z + bv.z, aw + wself * hs.w + bv.w);
    *(float4*)(out + (size_t)node * 256 + ch) = o;
}

// ---------------- launch ----------------

static inline char* align16(char* p) { return (char*)(((size_t)p + 15) & ~(size_t)15); }

extern "C" void kernel_launch(void* const* d_in, const int* in_sizes, int n_in,
                              void* d_out, int out_size, void* d_ws, size_t ws_size,
                              hipStream_t stream) {
    const float* x  = (const float*)d_in[0];
    const int* eidx = (const int*)d_in[1];
    const float* W1 = (const float*)d_in[2];
    const float* b1 = (const float*)d_in[3];
    const float* W2 = (const float*)d_in[4];
    const float* b2 = (const float*)d_in[5];
    const float* W3 = (const float*)d_in[6];
    const float* b3 = (const float*)d_in[7];
    float* out = (float*)d_out;

    const int* src = eidx;
    const int* dst = eidx + N_EDGES;

    char* ws = (char*)d_ws;
    unsigned short* A2 = (unsigned short*)ws;  ws += (size_t)MPAD * KPHYS * 2;   // 102.5 MB
    float* Cbuf = (float*)ws;                  ws += (size_t)MPAD * 512 * 4;      // 102.5 MB
    __half* C16 = (__half*)ws;                 ws += (size_t)MPAD * 512 * 2;      // 51.2 MB
    unsigned short* B2T1 = (unsigned short*)ws; ws += (size_t)512 * KVIRT * 2;
    unsigned short* B2T2 = (unsigned short*)ws; ws += (size_t)512 * KVIRT * 2;
    unsigned short* B2T3 = (unsigned short*)ws; ws += (size_t)256 * KVIRT * 2;
    int* deg = (int*)ws;        ws = align16(ws + (size_t)N_NODES * 4);
    float* dinv = (float*)ws;   ws = align16(ws + (size_t)N_NODES * 4);
    int* offsets = (int*)ws;    ws = align16(ws + (size_t)(N_NODES + 1) * 4);
    int* cursor = (int*)ws;     ws = align16(ws + (size_t)N_NODES * 4);
    int* csr_src = (int*)ws;    ws = align16(ws + (size_t)N_EDGES * 4);
    float* csr_w = (float*)ws;  ws = align16(ws + (size_t)N_EDGES * 4);

    // ---- CSR build ----
    zero_int_kernel<<<(N_NODES + 255) / 256, 256, 0, stream>>>(deg, N_NODES);
    count_deg_kernel<<<(N_EDGES + 255) / 256, 256, 0, stream>>>(dst, deg);
    dinv_kernel<<<(N_NODES + 255) / 256, 256, 0, stream>>>(deg, dinv);
    scan_kernel<<<1, 1024, 0, stream>>>(deg, offsets, cursor);
    fill_csr_kernel<<<(N_EDGES + 255) / 256, 256, 0, stream>>>(src, dst, cursor, csr_src, csr_w, dinv);

    // ---- weight + input splits ----
    wsplit_kernel<<<(512 * 512 + 255) / 256, 256, 0, stream>>>(W1, B2T1, 512);
    wsplit_kernel<<<(512 * 512 + 255) / 256, 256, 0, stream>>>(W2, B2T2, 512);
    wsplit_kernel<<<(512 * 256 + 255) / 256, 256, 0, stream>>>(W3, B2T3, 256);
    split_x_kernel<<<MPAD, 256, 0, stream>>>(x, A2);

    // ---- layer 1 ----
    {
        dim3 grid(512 / 128, MPAD / 128);  // x = col block, y = row band
        gemm_split_bt<<<grid, 256, 0, stream>>>(A2, B2T1, Cbuf, C16, 512);
        aggregate_split_kernel<<<MPAD / 4, 256, 0, stream>>>(Cbuf, C16, offsets, csr_src, csr_w, dinv, b1, A2);
    }
    // ---- layer 2 ----
    {
        dim3 grid(512 / 128, MPAD / 128);
        gemm_split_bt<<<grid, 256, 0, stream>>>(A2, B2T2, Cbuf, C16, 512);
        aggregate_split_kernel<<<MPAD / 4, 256, 0, stream>>>(Cbuf, C16, offsets, csr_src, csr_w, dinv, b2, A2);
    }
    // ---- layer 3 ----
    {
        dim3 grid(256 / 128, MPAD / 128);
        gemm_split_bt<<<grid, 256, 0, stream>>>(A2, B2T3, Cbuf, C16, 256);
        aggregate_final_kernel<<<MPAD / 4, 256, 0, stream>>>(Cbuf, C16, offsets, csr_src, csr_w, dinv, b3, out);
    }
}